// Round 13
// baseline (652.413 us; speedup 1.0000x reference)
//
#include <hip/hip_runtime.h>

#define KOFF 27
#define MPAIR 100000
#define NPAIR (KOFF * MPAIR)        // 2,700,000
#define NIN 200000
#define NOUT 400000
#define CIN 32
#define COUT 32

#define ROWS_PER_BIN 256
#define NBIN ((NOUT + ROWS_PER_BIN - 1) / ROWS_PER_BIN)   // 1563 (out bins)
#define CAPB 3072
#define BPB 8192
#define SPILL_CAP 65536

#define CHROWS 1024                 // in_row chunk size
#define NCHUNK ((NIN + CHROWS - 1) / CHROWS)              // 196
#define NBINC (KOFF * NCHUNK)       // 5292 (k,chunk) bins

// ---------- workspace layout (bytes) ----------
#define O_CNTC    ((size_t)8192)
#define O_SPCNT   ((size_t)32768)
#define O_SPILL   ((size_t)33024)
#define O_BASC    ((size_t)560128)
#define O_CURC    ((size_t)581632)
#define O_BINNED  ((size_t)603136)
#define O_BINI    ((size_t)19809280)
#define O_PEROFF  ((size_t)30609280)
#define O_F16     ((size_t)203409280)
#define WS_NEED   ((size_t)216209280)

typedef unsigned int uint4n __attribute__((ext_vector_type(4)));

__device__ __forceinline__ unsigned int bf16pair(float a, float b) {
    unsigned int ua = __float_as_uint(a), ub = __float_as_uint(b);
    ua = (ua + 0x7fffu + ((ua >> 16) & 1u)) >> 16;   // RNE
    ub = (ub + 0x7fffu + ((ub >> 16) & 1u)) >> 16;
    return ua | (ub << 16);
}
__device__ __forceinline__ float bf2f(unsigned short v) {
    return __uint_as_float(((unsigned int)v) << 16);
}
__device__ __forceinline__ float bf2f_lo(unsigned int w) {
    return __uint_as_float(w << 16);
}
__device__ __forceinline__ float bf2f_hi(unsigned int w) {
    return __uint_as_float(w & 0xFFFF0000u);
}

// ---------- Phase 0: feats f32 -> bf16 ----------
__global__ __launch_bounds__(256) void cvt_kernel(
    const float* __restrict__ feats, unsigned short* __restrict__ f16)
{
    int i = blockIdx.x * 256 + threadIdx.x;          // one thread = 8 elements
    if (i >= NIN * CIN / 8) return;
    const float4* src = reinterpret_cast<const float4*>(feats) + i * 2;
    float4 a = src[0], b = src[1];
    uint4n u;
    u.x = bf16pair(a.x, a.y); u.y = bf16pair(a.z, a.w);
    u.z = bf16pair(b.x, b.y); u.w = bf16pair(b.z, b.w);
    reinterpret_cast<uint4n*>(f16)[i] = u;
}

// ---------- Phase A1: histogram (k, in_row chunk) ----------
__global__ __launch_bounds__(256) void histc_kernel(
    const int* __restrict__ in_map, int* __restrict__ cntc)
{
    __shared__ int h[NBINC];                 // 21 KB
    const int t = threadIdx.x;
    const int base = blockIdx.x * BPB;
    for (int c = t; c < NBINC; c += 256) h[c] = 0;
    __syncthreads();
    for (int i = t; i < BPB; i += 256) {
        int p = base + i;
        if (p < NPAIR) {
            int key = (p / MPAIR) * NCHUNK + (in_map[p] >> 10);
            atomicAdd(&h[key], 1);
        }
    }
    __syncthreads();
    for (int c = t; c < NBINC; c += 256) if (h[c]) atomicAdd(&cntc[c], h[c]);
}

// ---------- Phase A2: exclusive scan over 5292 bins (single block) ----------
__global__ __launch_bounds__(256) void scanc_kernel(
    const int* __restrict__ cntc, int* __restrict__ basc, int* __restrict__ curc)
{
    __shared__ int lsum[256];
    const int t = threadIdx.x;
    int v[21]; int s = 0;
#pragma unroll
    for (int j = 0; j < 21; ++j) {
        int i = t * 21 + j;
        v[j] = (i < NBINC) ? cntc[i] : 0;
        s += v[j];
    }
    lsum[t] = s;
    __syncthreads();
    for (int off = 1; off < 256; off <<= 1) {
        int w = (t >= off) ? lsum[t - off] : 0;
        __syncthreads();
        lsum[t] += w;
        __syncthreads();
    }
    int run = lsum[t] - s;
#pragma unroll
    for (int j = 0; j < 21; ++j) {
        int i = t * 21 + j;
        if (i < NBINC) { basc[i] = run; curc[i] = run; run += v[j]; }
    }
    if (t == 255) basc[NBINC] = run;
}

// ---------- Phase A3: chunk-local scatter into (k,chunk) bins ----------
__global__ __launch_bounds__(256) void scatc_kernel(
    const int* __restrict__ in_map, int* __restrict__ curc,
    unsigned int* __restrict__ binned_in)
{
    __shared__ int h[NBINC];                 // count, then absolute cursor
    const int t = threadIdx.x;
    const int base = blockIdx.x * BPB;
    for (int c = t; c < NBINC; c += 256) h[c] = 0;
    __syncthreads();
    for (int i = t; i < BPB; i += 256) {
        int p = base + i;
        if (p < NPAIR)
            atomicAdd(&h[(p / MPAIR) * NCHUNK + (in_map[p] >> 10)], 1);
    }
    __syncthreads();
    for (int c = t; c < NBINC; c += 256) {
        int v = h[c];
        h[c] = v ? atomicAdd(&curc[c], v) : 0;   // reserve chunk -> abs base
    }
    __syncthreads();
    for (int i = t; i < BPB; i += 256) {
        int p = base + i;
        if (p >= NPAIR) continue;
        int ir = in_map[p];
        int key = (p / MPAIR) * NCHUNK + (ir >> 10);
        int slot = atomicAdd(&h[key], 1);
        // UNSIGNED pack: rl(10b @22..31) | pair(22b). (R12 bug: signed overflow)
        binned_in[slot] = ((unsigned int)(ir & 1023) << 22) | (unsigned int)p;
    }
}

// ---------- Phase 1: multisplit pair ids by output-row bin ----------
__global__ __launch_bounds__(256) void bin_kernel(
    const int* __restrict__ out_map,
    int* __restrict__ gbin, int* __restrict__ binned,
    int* __restrict__ spill_cnt, int2* __restrict__ spill)
{
    __shared__ int lhist[NBIN];
    const int t = threadIdx.x;
    const int base = blockIdx.x * BPB;

    for (int c = t; c < NBIN; c += 256) lhist[c] = 0;
    __syncthreads();

    for (int i = t; i < BPB; i += 256) {
        int p = base + i;
        if (p < NPAIR) atomicAdd(&lhist[out_map[p] >> 8], 1);
    }
    __syncthreads();

    for (int c = t; c < NBIN; c += 256) {
        int cnt = lhist[c];
        lhist[c] = (cnt > 0) ? atomicAdd(&gbin[c], cnt) : 0;
    }
    __syncthreads();

    for (int i = t; i < BPB; i += 256) {
        int p = base + i;
        if (p >= NPAIR) continue;
        int row = out_map[p];
        int bin = row >> 8;
        int val = ((row & 255) << 22) | p;       // max bit 29: sign-safe
        int pos = atomicAdd(&lhist[bin], 1);
        if (pos < CAPB) {
            binned[(size_t)bin * CAPB + pos] = val;
        } else {
            int o = atomicAdd(spill_cnt, 1);
            if (o < SPILL_CAP) spill[o] = make_int2(row, p);
        }
    }
}

// ---------- Phase 2: mv3 — (k,chunk)-binned matvec, L2-windowed gather ----------
__global__ __launch_bounds__(256) void mv3_kernel(
    const unsigned short* __restrict__ f16, const float* __restrict__ weight,
    const int* __restrict__ basc, const unsigned int* __restrict__ binned_in,
    unsigned short* __restrict__ per_off)
{
    // XCD-swizzled bin mapping: 27 k-bins of one chunk land on one XCD.
    int g = blockIdx.x;
    int k, chunk;
    if (g < 24 * 216) {
        int grp = g / 216, rem = g % 216;
        k = rem >> 3;                       // 0..26
        chunk = grp * 8 + (rem & 7);
    } else {
        int tl = g - 24 * 216;              // 0..107
        k = tl >> 2;
        chunk = 192 + (tl & 3);
    }
    const int key = k * NCHUNK + chunk;
    const int s0 = basc[key], s1 = basc[key + 1];
    const int t = threadIdx.x;

    const float* wk = weight + (size_t)k * (CIN * COUT);  // wave-uniform -> SGPR

    for (int i = s0 + t; i < s1; i += 256) {
        unsigned int e = binned_in[i];       // coalesced
        int rl = (int)(e >> 22);             // logical shift: unsigned
        int p  = (int)(e & 0x3FFFFFu);
        int row = (chunk << 10) + rl;        // inside the 64 KB L2-hot window

        const uint4n* frow = reinterpret_cast<const uint4n*>(f16 + (size_t)row * CIN);
        uint4n q0 = frow[0], q1 = frow[1], q2 = frow[2], q3 = frow[3];  // MLP4

        float f[CIN];
        f[0] = bf2f_lo(q0.x);  f[1] = bf2f_hi(q0.x);
        f[2] = bf2f_lo(q0.y);  f[3] = bf2f_hi(q0.y);
        f[4] = bf2f_lo(q0.z);  f[5] = bf2f_hi(q0.z);
        f[6] = bf2f_lo(q0.w);  f[7] = bf2f_hi(q0.w);
        f[8] = bf2f_lo(q1.x);  f[9] = bf2f_hi(q1.x);
        f[10] = bf2f_lo(q1.y); f[11] = bf2f_hi(q1.y);
        f[12] = bf2f_lo(q1.z); f[13] = bf2f_hi(q1.z);
        f[14] = bf2f_lo(q1.w); f[15] = bf2f_hi(q1.w);
        f[16] = bf2f_lo(q2.x); f[17] = bf2f_hi(q2.x);
        f[18] = bf2f_lo(q2.y); f[19] = bf2f_hi(q2.y);
        f[20] = bf2f_lo(q2.z); f[21] = bf2f_hi(q2.z);
        f[22] = bf2f_lo(q2.w); f[23] = bf2f_hi(q2.w);
        f[24] = bf2f_lo(q3.x); f[25] = bf2f_hi(q3.x);
        f[26] = bf2f_lo(q3.y); f[27] = bf2f_hi(q3.y);
        f[28] = bf2f_lo(q3.z); f[29] = bf2f_hi(q3.z);
        f[30] = bf2f_lo(q3.w); f[31] = bf2f_hi(q3.w);

        float acc[COUT];
#pragma unroll
        for (int j = 0; j < COUT; ++j) acc[j] = 0.f;
#pragma unroll
        for (int ci = 0; ci < CIN; ++ci) {
            float fv = f[ci];
#pragma unroll
            for (int co = 0; co < COUT; ++co)
                acc[co] = fmaf(fv, wk[ci * COUT + co], acc[co]);
        }

        uint4n u;
        uint4n* dst = reinterpret_cast<uint4n*>(per_off + (size_t)p * COUT);
#pragma unroll
        for (int j = 0; j < 4; ++j) {
            u.x = bf16pair(acc[8 * j + 0], acc[8 * j + 1]);
            u.y = bf16pair(acc[8 * j + 2], acc[8 * j + 3]);
            u.z = bf16pair(acc[8 * j + 4], acc[8 * j + 5]);
            u.w = bf16pair(acc[8 * j + 6], acc[8 * j + 7]);
            dst[j] = u;                      // random 64B store, fire-and-forget
        }
    }
}

// ---------- Phase 3: per-bin counting-sort + ILP4 gather ----------
__global__ __launch_bounds__(256) void gather3_kernel(
    const unsigned short* __restrict__ per_off,
    const int* __restrict__ gbin, const int* __restrict__ binned,
    float* __restrict__ out)
{
    __shared__ int sorted[CAPB];             // 12 KB
    __shared__ int cnt[ROWS_PER_BIN];
    __shared__ int scn[ROWS_PER_BIN];
    __shared__ int cur[ROWS_PER_BIN];

    const int bin = blockIdx.x;
    const int t = threadIdx.x;
    const int n = min(gbin[bin], CAPB);
    const int* mybin = binned + (size_t)bin * CAPB;

    cnt[t] = 0;
    __syncthreads();

    for (int i = t; i < n; i += 256)
        atomicAdd(&cnt[(mybin[i] >> 22) & 255], 1);
    __syncthreads();

    scn[t] = cnt[t];
    __syncthreads();
#pragma unroll
    for (int off = 1; off < 256; off <<= 1) {
        int v = (t >= off) ? scn[t - off] : 0;
        __syncthreads();
        scn[t] += v;
        __syncthreads();
    }
    cur[t] = scn[t] - cnt[t];
    __syncthreads();

    for (int i = t; i < n; i += 256) {
        int v = mybin[i];
        int pos = atomicAdd(&cur[(v >> 22) & 255], 1);
        sorted[pos] = v & 0x3FFFFF;
    }
    __syncthreads();

    const int g = t >> 5, lane = t & 31;
    for (int r = g; r < ROWS_PER_BIN; r += 8) {
        int grow = (bin << 8) + r;
        if (grow >= NOUT) break;
        int s1 = scn[r], s0 = s1 - cnt[r];
        float a0 = 0.f, a1 = 0.f, a2 = 0.f, a3 = 0.f;
        int i = s0;
        for (; i + 4 <= s1; i += 4) {
            int p0 = sorted[i], p1 = sorted[i + 1], p2 = sorted[i + 2], p3 = sorted[i + 3];
            a0 += bf2f(per_off[(size_t)p0 * COUT + lane]);
            a1 += bf2f(per_off[(size_t)p1 * COUT + lane]);
            a2 += bf2f(per_off[(size_t)p2 * COUT + lane]);
            a3 += bf2f(per_off[(size_t)p3 * COUT + lane]);
        }
        for (; i < s1; ++i)
            a0 += bf2f(per_off[(size_t)sorted[i] * COUT + lane]);
        out[(size_t)grow * COUT + lane] = (a0 + a1) + (a2 + a3);
    }
}

// ---------- Phase 4: rare out-bin overflow, recompute + atomics ----------
__global__ __launch_bounds__(256) void spill_kernel(
    const float* __restrict__ feats, const float* __restrict__ weight,
    const int* __restrict__ in_map,
    const int* __restrict__ spill_cnt, const int2* __restrict__ spill,
    float* __restrict__ out)
{
    int n = min(*spill_cnt, SPILL_CAP);
    for (int i = blockIdx.x * blockDim.x + threadIdx.x; i < n * 32;
         i += gridDim.x * blockDim.x) {
        int idx = i >> 5, co = i & 31;
        int2 s = spill[idx];
        int row = s.x;
        int p   = s.y;
        int k   = p / MPAIR;
        int irow = in_map[p];
        const float* f  = feats + (size_t)irow * CIN;
        const float* wk = weight + (size_t)k * (CIN * COUT);
        float acc = 0.f;
#pragma unroll
        for (int ci = 0; ci < CIN; ++ci)
            acc = fmaf(f[ci], wk[ci * COUT + co], acc);
        atomicAdd(&out[(size_t)row * COUT + co], acc);
    }
}

// ---------- last-resort fallback (tiny ws): R1 atomic scatter ----------
__global__ __launch_bounds__(256) void spconvt_fallback(
    const float* __restrict__ feats, const float* __restrict__ weight,
    const int* __restrict__ in_map, const int* __restrict__ out_map,
    float* __restrict__ out)
{
    const int k = blockIdx.y;
    const int m = blockIdx.x * blockDim.x + threadIdx.x;
    const bool active = (m < MPAIR);
    const int mm = active ? m : (MPAIR - 1);
    const int pair = k * MPAIR + mm;
    const int in_row = in_map[pair];
    const int out_row = out_map[pair];
    const float4* frow = reinterpret_cast<const float4*>(feats + (size_t)in_row * CIN);
    float4 f4[8];
#pragma unroll
    for (int i = 0; i < 8; ++i) f4[i] = frow[i];
    const float* f = reinterpret_cast<const float*>(f4);
    float acc[COUT];
#pragma unroll
    for (int i = 0; i < COUT; ++i) acc[i] = 0.f;
    const float* wk = weight + (size_t)k * (CIN * COUT);
#pragma unroll
    for (int ci = 0; ci < CIN; ++ci) {
        const float fv = f[ci];
#pragma unroll
        for (int co = 0; co < COUT; ++co)
            acc[co] = fmaf(fv, wk[ci * COUT + co], acc[co]);
    }
    if (active) {
        float* orow = out + (size_t)out_row * COUT;
#pragma unroll
        for (int co = 0; co < COUT; ++co) atomicAdd(orow + co, acc[co]);
    }
}

extern "C" void kernel_launch(void* const* d_in, const int* in_sizes, int n_in,
                              void* d_out, int out_size, void* d_ws, size_t ws_size,
                              hipStream_t stream) {
    const float* feats  = (const float*)d_in[0];
    const float* weight = (const float*)d_in[1];
    const int* in_map   = (const int*)d_in[2];
    const int* out_map  = (const int*)d_in[3];
    float* out          = (float*)d_out;
    char* ws            = (char*)d_ws;

    if (ws_size >= WS_NEED) {
        int* gbin               = (int*)(ws);
        int* cntc               = (int*)(ws + O_CNTC);
        int* spill_cnt          = (int*)(ws + O_SPCNT);
        int2* spill             = (int2*)(ws + O_SPILL);
        int* basc               = (int*)(ws + O_BASC);
        int* curc               = (int*)(ws + O_CURC);
        int* binned             = (int*)(ws + O_BINNED);
        unsigned int* binned_in = (unsigned int*)(ws + O_BINI);
        unsigned short* per_off = (unsigned short*)(ws + O_PEROFF);
        unsigned short* f16     = (unsigned short*)(ws + O_F16);

        (void)hipMemsetAsync(ws, 0, O_SPILL, stream);   // gbin + cntc + spill_cnt

        cvt_kernel<<<dim3((NIN * CIN / 8 + 255) / 256), dim3(256), 0, stream>>>(
            feats, f16);

        histc_kernel<<<dim3((NPAIR + BPB - 1) / BPB), dim3(256), 0, stream>>>(
            in_map, cntc);
        scanc_kernel<<<dim3(1), dim3(256), 0, stream>>>(cntc, basc, curc);
        scatc_kernel<<<dim3((NPAIR + BPB - 1) / BPB), dim3(256), 0, stream>>>(
            in_map, curc, binned_in);

        bin_kernel<<<dim3((NPAIR + BPB - 1) / BPB), dim3(256), 0, stream>>>(
            out_map, gbin, binned, spill_cnt, spill);

        mv3_kernel<<<dim3(NBINC), dim3(256), 0, stream>>>(
            f16, weight, basc, binned_in, per_off);

        gather3_kernel<<<dim3(NBIN), dim3(256), 0, stream>>>(
            per_off, gbin, binned, out);

        spill_kernel<<<dim3(64), dim3(256), 0, stream>>>(
            feats, weight, in_map, spill_cnt, spill, out);
    } else {
        (void)hipMemsetAsync(d_out, 0, (size_t)out_size * sizeof(float), stream);
        spconvt_fallback<<<dim3((MPAIR + 255) / 256, KOFF), dim3(256), 0, stream>>>(
            feats, weight, in_map, out_map, out);
    }
}

// Round 14
// 648.367 us; speedup vs baseline: 1.0062x; 1.0062x over previous
//
#include <hip/hip_runtime.h>

#define KOFF 27
#define MPAIR 100000
#define NPAIR (KOFF * MPAIR)        // 2,700,000
#define NIN 200000
#define NOUT 400000
#define CIN 32
#define COUT 32

#define ROWS_PER_BIN 256
#define NBIN ((NOUT + ROWS_PER_BIN - 1) / ROWS_PER_BIN)   // 1563 (out bins)
#define CAPB 3072
#define BPB 8192
#define SPILL_CAP 65536

#define CHROWS 1024                 // in_row chunk size
#define NCHUNK ((NIN + CHROWS - 1) / CHROWS)              // 196
#define NBINC (KOFF * NCHUNK)       // 5292 (k,chunk) bins

// ---------- workspace layout (bytes) ----------
#define O_CNTC    ((size_t)8192)
#define O_SPCNT   ((size_t)32768)
#define O_SPILL   ((size_t)33024)
#define O_BASC    ((size_t)560128)
#define O_CURC    ((size_t)581632)
#define O_BINNED  ((size_t)603136)
#define O_BINI    ((size_t)19809280)
#define O_PEROFF  ((size_t)30609280)
#define O_F16     ((size_t)203409280)
#define WS_NEED   ((size_t)216209280)

typedef unsigned int uint4n __attribute__((ext_vector_type(4)));

__device__ __forceinline__ unsigned int bf16pair(float a, float b) {
    unsigned int ua = __float_as_uint(a), ub = __float_as_uint(b);
    ua = (ua + 0x7fffu + ((ua >> 16) & 1u)) >> 16;   // RNE
    ub = (ub + 0x7fffu + ((ub >> 16) & 1u)) >> 16;
    return ua | (ub << 16);
}
__device__ __forceinline__ float bf2f(unsigned short v) {
    return __uint_as_float(((unsigned int)v) << 16);
}
__device__ __forceinline__ float bf2f_lo(unsigned int w) {
    return __uint_as_float(w << 16);
}
__device__ __forceinline__ float bf2f_hi(unsigned int w) {
    return __uint_as_float(w & 0xFFFF0000u);
}

// ---------- Phase 0: feats f32 -> bf16 ----------
__global__ __launch_bounds__(256) void cvt_kernel(
    const float* __restrict__ feats, unsigned short* __restrict__ f16)
{
    int i = blockIdx.x * 256 + threadIdx.x;          // one thread = 8 elements
    if (i >= NIN * CIN / 8) return;
    const float4* src = reinterpret_cast<const float4*>(feats) + i * 2;
    float4 a = src[0], b = src[1];
    uint4n u;
    u.x = bf16pair(a.x, a.y); u.y = bf16pair(a.z, a.w);
    u.z = bf16pair(b.x, b.y); u.w = bf16pair(b.z, b.w);
    reinterpret_cast<uint4n*>(f16)[i] = u;
}

// ---------- Phase A1: histogram (k, in_row chunk) ----------
__global__ __launch_bounds__(256) void histc_kernel(
    const int* __restrict__ in_map, int* __restrict__ cntc)
{
    __shared__ int h[NBINC];                 // 21 KB
    const int t = threadIdx.x;
    const int base = blockIdx.x * BPB;
    for (int c = t; c < NBINC; c += 256) h[c] = 0;
    __syncthreads();
    for (int i = t; i < BPB; i += 256) {
        int p = base + i;
        if (p < NPAIR) {
            int key = (p / MPAIR) * NCHUNK + (in_map[p] >> 10);
            atomicAdd(&h[key], 1);
        }
    }
    __syncthreads();
    for (int c = t; c < NBINC; c += 256) if (h[c]) atomicAdd(&cntc[c], h[c]);
}

// ---------- Phase A2: exclusive scan over 5292 bins (single block) ----------
__global__ __launch_bounds__(256) void scanc_kernel(
    const int* __restrict__ cntc, int* __restrict__ basc, int* __restrict__ curc)
{
    __shared__ int lsum[256];
    const int t = threadIdx.x;
    int v[21]; int s = 0;
#pragma unroll
    for (int j = 0; j < 21; ++j) {
        int i = t * 21 + j;
        v[j] = (i < NBINC) ? cntc[i] : 0;
        s += v[j];
    }
    lsum[t] = s;
    __syncthreads();
    for (int off = 1; off < 256; off <<= 1) {
        int w = (t >= off) ? lsum[t - off] : 0;
        __syncthreads();
        lsum[t] += w;
        __syncthreads();
    }
    int run = lsum[t] - s;
#pragma unroll
    for (int j = 0; j < 21; ++j) {
        int i = t * 21 + j;
        if (i < NBINC) { basc[i] = run; curc[i] = run; run += v[j]; }
    }
    if (t == 255) basc[NBINC] = run;
}

// ---------- Phase A3: chunk-local scatter into (k,chunk) bins ----------
__global__ __launch_bounds__(256) void scatc_kernel(
    const int* __restrict__ in_map, int* __restrict__ curc,
    unsigned int* __restrict__ binned_in)
{
    __shared__ int h[NBINC];                 // count, then absolute cursor
    const int t = threadIdx.x;
    const int base = blockIdx.x * BPB;
    for (int c = t; c < NBINC; c += 256) h[c] = 0;
    __syncthreads();
    for (int i = t; i < BPB; i += 256) {
        int p = base + i;
        if (p < NPAIR)
            atomicAdd(&h[(p / MPAIR) * NCHUNK + (in_map[p] >> 10)], 1);
    }
    __syncthreads();
    for (int c = t; c < NBINC; c += 256) {
        int v = h[c];
        h[c] = v ? atomicAdd(&curc[c], v) : 0;   // reserve chunk -> abs base
    }
    __syncthreads();
    for (int i = t; i < BPB; i += 256) {
        int p = base + i;
        if (p >= NPAIR) continue;
        int ir = in_map[p];
        int key = (p / MPAIR) * NCHUNK + (ir >> 10);
        int slot = atomicAdd(&h[key], 1);
        binned_in[slot] = ((unsigned int)(ir & 1023) << 22) | (unsigned int)p;
    }
}

// ---------- Phase 1: multisplit pair ids by output-row bin ----------
__global__ __launch_bounds__(256) void bin_kernel(
    const int* __restrict__ out_map,
    int* __restrict__ gbin, int* __restrict__ binned,
    int* __restrict__ spill_cnt, int2* __restrict__ spill)
{
    __shared__ int lhist[NBIN];
    const int t = threadIdx.x;
    const int base = blockIdx.x * BPB;

    for (int c = t; c < NBIN; c += 256) lhist[c] = 0;
    __syncthreads();

    for (int i = t; i < BPB; i += 256) {
        int p = base + i;
        if (p < NPAIR) atomicAdd(&lhist[out_map[p] >> 8], 1);
    }
    __syncthreads();

    for (int c = t; c < NBIN; c += 256) {
        int cnt = lhist[c];
        lhist[c] = (cnt > 0) ? atomicAdd(&gbin[c], cnt) : 0;
    }
    __syncthreads();

    for (int i = t; i < BPB; i += 256) {
        int p = base + i;
        if (p >= NPAIR) continue;
        int row = out_map[p];
        int bin = row >> 8;
        int val = ((row & 255) << 22) | p;       // max bit 29: sign-safe
        int pos = atomicAdd(&lhist[bin], 1);
        if (pos < CAPB) {
            binned[(size_t)bin * CAPB + pos] = val;
        } else {
            int o = atomicAdd(spill_cnt, 1);
            if (o < SPILL_CAP) spill[o] = make_int2(row, p);
        }
    }
}

// ---------- Phase 2: mv3 — (k,chunk)-binned matvec, SGPR weights restored ----------
__global__ __launch_bounds__(256) void mv3_kernel(
    const unsigned short* __restrict__ f16, const float* __restrict__ weight,
    const int* __restrict__ basc, const unsigned int* __restrict__ binned_in,
    unsigned short* __restrict__ per_off)
{
    // XCD-swizzled bin mapping: 27 k-bins of one chunk land on one XCD.
    int g = blockIdx.x;
    int k, chunk;
    if (g < 24 * 216) {
        int grp = g / 216, rem = g % 216;
        k = rem >> 3;                       // 0..26
        chunk = grp * 8 + (rem & 7);
    } else {
        int tl = g - 24 * 216;              // 0..107
        k = tl >> 2;
        chunk = 192 + (tl & 3);
    }
    // R13 bug: if/else-derived k marked divergent -> weight reads became
    // per-lane VMEM (VALUBusy 89%). Force back to SGPR:
    k = __builtin_amdgcn_readfirstlane(k);
    chunk = __builtin_amdgcn_readfirstlane(chunk);

    const int key = k * NCHUNK + chunk;
    const int s0 = basc[key], s1 = basc[key + 1];
    const int t = threadIdx.x;

    const float* wk = weight + (size_t)k * (CIN * COUT);  // SGPR base -> s_load

    for (int i = s0 + t; i < s1; i += 256) {
        unsigned int e = binned_in[i];       // coalesced
        int rl = (int)(e >> 22);
        int p  = (int)(e & 0x3FFFFFu);
        int row = (chunk << 10) + rl;        // inside the 64 KB L2-hot window

        const uint4n* frow = reinterpret_cast<const uint4n*>(f16 + (size_t)row * CIN);
        uint4n q0 = frow[0], q1 = frow[1], q2 = frow[2], q3 = frow[3];  // MLP4

        float f[CIN];
        f[0] = bf2f_lo(q0.x);  f[1] = bf2f_hi(q0.x);
        f[2] = bf2f_lo(q0.y);  f[3] = bf2f_hi(q0.y);
        f[4] = bf2f_lo(q0.z);  f[5] = bf2f_hi(q0.z);
        f[6] = bf2f_lo(q0.w);  f[7] = bf2f_hi(q0.w);
        f[8] = bf2f_lo(q1.x);  f[9] = bf2f_hi(q1.x);
        f[10] = bf2f_lo(q1.y); f[11] = bf2f_hi(q1.y);
        f[12] = bf2f_lo(q1.z); f[13] = bf2f_hi(q1.z);
        f[14] = bf2f_lo(q1.w); f[15] = bf2f_hi(q1.w);
        f[16] = bf2f_lo(q2.x); f[17] = bf2f_hi(q2.x);
        f[18] = bf2f_lo(q2.y); f[19] = bf2f_hi(q2.y);
        f[20] = bf2f_lo(q2.z); f[21] = bf2f_hi(q2.z);
        f[22] = bf2f_lo(q2.w); f[23] = bf2f_hi(q2.w);
        f[24] = bf2f_lo(q3.x); f[25] = bf2f_hi(q3.x);
        f[26] = bf2f_lo(q3.y); f[27] = bf2f_hi(q3.y);
        f[28] = bf2f_lo(q3.z); f[29] = bf2f_hi(q3.z);
        f[30] = bf2f_lo(q3.w); f[31] = bf2f_hi(q3.w);

        float acc[COUT];
#pragma unroll
        for (int j = 0; j < COUT; ++j) acc[j] = 0.f;
#pragma unroll
        for (int ci = 0; ci < CIN; ++ci) {
            float fv = f[ci];
#pragma unroll
            for (int co = 0; co < COUT; ++co)
                acc[co] = fmaf(fv, wk[ci * COUT + co], acc[co]);
        }

        uint4n u;
        uint4n* dst = reinterpret_cast<uint4n*>(per_off + (size_t)p * COUT);
#pragma unroll
        for (int j = 0; j < 4; ++j) {
            u.x = bf16pair(acc[8 * j + 0], acc[8 * j + 1]);
            u.y = bf16pair(acc[8 * j + 2], acc[8 * j + 3]);
            u.z = bf16pair(acc[8 * j + 4], acc[8 * j + 5]);
            u.w = bf16pair(acc[8 * j + 6], acc[8 * j + 7]);
            dst[j] = u;                      // random 64B store, fire-and-forget
        }
    }
}

// ---------- Phase 3: per-bin counting-sort + ILP4 gather ----------
__global__ __launch_bounds__(256) void gather3_kernel(
    const unsigned short* __restrict__ per_off,
    const int* __restrict__ gbin, const int* __restrict__ binned,
    float* __restrict__ out)
{
    __shared__ int sorted[CAPB];             // 12 KB
    __shared__ int cnt[ROWS_PER_BIN];
    __shared__ int scn[ROWS_PER_BIN];
    __shared__ int cur[ROWS_PER_BIN];

    const int bin = blockIdx.x;
    const int t = threadIdx.x;
    const int n = min(gbin[bin], CAPB);
    const int* mybin = binned + (size_t)bin * CAPB;

    cnt[t] = 0;
    __syncthreads();

    for (int i = t; i < n; i += 256)
        atomicAdd(&cnt[(mybin[i] >> 22) & 255], 1);
    __syncthreads();

    scn[t] = cnt[t];
    __syncthreads();
#pragma unroll
    for (int off = 1; off < 256; off <<= 1) {
        int v = (t >= off) ? scn[t - off] : 0;
        __syncthreads();
        scn[t] += v;
        __syncthreads();
    }
    cur[t] = scn[t] - cnt[t];
    __syncthreads();

    for (int i = t; i < n; i += 256) {
        int v = mybin[i];
        int pos = atomicAdd(&cur[(v >> 22) & 255], 1);
        sorted[pos] = v & 0x3FFFFF;
    }
    __syncthreads();

    const int g = t >> 5, lane = t & 31;
    for (int r = g; r < ROWS_PER_BIN; r += 8) {
        int grow = (bin << 8) + r;
        if (grow >= NOUT) break;
        int s1 = scn[r], s0 = s1 - cnt[r];
        float a0 = 0.f, a1 = 0.f, a2 = 0.f, a3 = 0.f;
        int i = s0;
        for (; i + 4 <= s1; i += 4) {
            int p0 = sorted[i], p1 = sorted[i + 1], p2 = sorted[i + 2], p3 = sorted[i + 3];
            a0 += bf2f(per_off[(size_t)p0 * COUT + lane]);
            a1 += bf2f(per_off[(size_t)p1 * COUT + lane]);
            a2 += bf2f(per_off[(size_t)p2 * COUT + lane]);
            a3 += bf2f(per_off[(size_t)p3 * COUT + lane]);
        }
        for (; i < s1; ++i)
            a0 += bf2f(per_off[(size_t)sorted[i] * COUT + lane]);
        out[(size_t)grow * COUT + lane] = (a0 + a1) + (a2 + a3);
    }
}

// ---------- Phase 4: rare out-bin overflow, recompute + atomics ----------
__global__ __launch_bounds__(256) void spill_kernel(
    const float* __restrict__ feats, const float* __restrict__ weight,
    const int* __restrict__ in_map,
    const int* __restrict__ spill_cnt, const int2* __restrict__ spill,
    float* __restrict__ out)
{
    int n = min(*spill_cnt, SPILL_CAP);
    for (int i = blockIdx.x * blockDim.x + threadIdx.x; i < n * 32;
         i += gridDim.x * blockDim.x) {
        int idx = i >> 5, co = i & 31;
        int2 s = spill[idx];
        int row = s.x;
        int p   = s.y;
        int k   = p / MPAIR;
        int irow = in_map[p];
        const float* f  = feats + (size_t)irow * CIN;
        const float* wk = weight + (size_t)k * (CIN * COUT);
        float acc = 0.f;
#pragma unroll
        for (int ci = 0; ci < CIN; ++ci)
            acc = fmaf(f[ci], wk[ci * COUT + co], acc);
        atomicAdd(&out[(size_t)row * COUT + co], acc);
    }
}

// ---------- last-resort fallback (tiny ws): R1 atomic scatter ----------
__global__ __launch_bounds__(256) void spconvt_fallback(
    const float* __restrict__ feats, const float* __restrict__ weight,
    const int* __restrict__ in_map, const int* __restrict__ out_map,
    float* __restrict__ out)
{
    const int k = blockIdx.y;
    const int m = blockIdx.x * blockDim.x + threadIdx.x;
    const bool active = (m < MPAIR);
    const int mm = active ? m : (MPAIR - 1);
    const int pair = k * MPAIR + mm;
    const int in_row = in_map[pair];
    const int out_row = out_map[pair];
    const float4* frow = reinterpret_cast<const float4*>(feats + (size_t)in_row * CIN);
    float4 f4[8];
#pragma unroll
    for (int i = 0; i < 8; ++i) f4[i] = frow[i];
    const float* f = reinterpret_cast<const float*>(f4);
    float acc[COUT];
#pragma unroll
    for (int i = 0; i < COUT; ++i) acc[i] = 0.f;
    const float* wk = weight + (size_t)k * (CIN * COUT);
#pragma unroll
    for (int ci = 0; ci < CIN; ++ci) {
        const float fv = f[ci];
#pragma unroll
        for (int co = 0; co < COUT; ++co)
            acc[co] = fmaf(fv, wk[ci * COUT + co], acc[co]);
    }
    if (active) {
        float* orow = out + (size_t)out_row * COUT;
#pragma unroll
        for (int co = 0; co < COUT; ++co) atomicAdd(orow + co, acc[co]);
    }
}

extern "C" void kernel_launch(void* const* d_in, const int* in_sizes, int n_in,
                              void* d_out, int out_size, void* d_ws, size_t ws_size,
                              hipStream_t stream) {
    const float* feats  = (const float*)d_in[0];
    const float* weight = (const float*)d_in[1];
    const int* in_map   = (const int*)d_in[2];
    const int* out_map  = (const int*)d_in[3];
    float* out          = (float*)d_out;
    char* ws            = (char*)d_ws;

    if (ws_size >= WS_NEED) {
        int* gbin               = (int*)(ws);
        int* cntc               = (int*)(ws + O_CNTC);
        int* spill_cnt          = (int*)(ws + O_SPCNT);
        int2* spill             = (int2*)(ws + O_SPILL);
        int* basc               = (int*)(ws + O_BASC);
        int* curc               = (int*)(ws + O_CURC);
        int* binned             = (int*)(ws + O_BINNED);
        unsigned int* binned_in = (unsigned int*)(ws + O_BINI);
        unsigned short* per_off = (unsigned short*)(ws + O_PEROFF);
        unsigned short* f16     = (unsigned short*)(ws + O_F16);

        (void)hipMemsetAsync(ws, 0, O_SPILL, stream);   // gbin + cntc + spill_cnt

        cvt_kernel<<<dim3((NIN * CIN / 8 + 255) / 256), dim3(256), 0, stream>>>(
            feats, f16);

        histc_kernel<<<dim3((NPAIR + BPB - 1) / BPB), dim3(256), 0, stream>>>(
            in_map, cntc);
        scanc_kernel<<<dim3(1), dim3(256), 0, stream>>>(cntc, basc, curc);
        scatc_kernel<<<dim3((NPAIR + BPB - 1) / BPB), dim3(256), 0, stream>>>(
            in_map, curc, binned_in);

        bin_kernel<<<dim3((NPAIR + BPB - 1) / BPB), dim3(256), 0, stream>>>(
            out_map, gbin, binned, spill_cnt, spill);

        mv3_kernel<<<dim3(NBINC), dim3(256), 0, stream>>>(
            f16, weight, basc, binned_in, per_off);

        gather3_kernel<<<dim3(NBIN), dim3(256), 0, stream>>>(
            per_off, gbin, binned, out);

        spill_kernel<<<dim3(64), dim3(256), 0, stream>>>(
            feats, weight, in_map, spill_cnt, spill, out);
    } else {
        (void)hipMemsetAsync(d_out, 0, (size_t)out_size * sizeof(float), stream);
        spconvt_fallback<<<dim3((MPAIR + 255) / 256, KOFF), dim3(256), 0, stream>>>(
            feats, weight, in_map, out_map, out);
    }
}

// Round 15
// 373.909 us; speedup vs baseline: 1.7448x; 1.7340x over previous
//
#include <hip/hip_runtime.h>

#define KOFF 27
#define MPAIR 100000
#define NPAIR (KOFF * MPAIR)        // 2,700,000
#define NIN 200000
#define NOUT 400000
#define CIN 32
#define COUT 32

#define ROWS_PER_BIN 256
#define NBIN ((NOUT + ROWS_PER_BIN - 1) / ROWS_PER_BIN)   // 1563 (out bins)
#define CAPB 3072
#define BPB 8192
#define SPILL_CAP 65536

#define CHROWS 1024                 // in_row chunk size
#define NCHUNK ((NIN + CHROWS - 1) / CHROWS)              // 196
#define NBINC (KOFF * NCHUNK)       // 5292 (k,chunk) bins

// ---------- workspace layout (bytes) ----------
#define O_CNTC    ((size_t)8192)
#define O_SPCNT   ((size_t)32768)
#define O_SPILL   ((size_t)33024)
#define O_BASC    ((size_t)560128)
#define O_CURC    ((size_t)581632)
#define O_BINNED  ((size_t)603136)
#define O_BINI    ((size_t)19809280)
#define O_PEROFF  ((size_t)30609280)
#define O_F16     ((size_t)203409280)
#define WS_NEED   ((size_t)216209280)

typedef unsigned int uint4n __attribute__((ext_vector_type(4)));

__device__ __forceinline__ unsigned int bf16pair(float a, float b) {
    unsigned int ua = __float_as_uint(a), ub = __float_as_uint(b);
    ua = (ua + 0x7fffu + ((ua >> 16) & 1u)) >> 16;   // RNE
    ub = (ub + 0x7fffu + ((ub >> 16) & 1u)) >> 16;
    return ua | (ub << 16);
}
__device__ __forceinline__ float bf2f(unsigned short v) {
    return __uint_as_float(((unsigned int)v) << 16);
}
__device__ __forceinline__ float bf2f_lo(unsigned int w) {
    return __uint_as_float(w << 16);
}
__device__ __forceinline__ float bf2f_hi(unsigned int w) {
    return __uint_as_float(w & 0xFFFF0000u);
}

// ---------- Phase 0: feats f32 -> bf16 ----------
__global__ __launch_bounds__(256) void cvt_kernel(
    const float* __restrict__ feats, unsigned short* __restrict__ f16)
{
    int i = blockIdx.x * 256 + threadIdx.x;          // one thread = 8 elements
    if (i >= NIN * CIN / 8) return;
    const float4* src = reinterpret_cast<const float4*>(feats) + i * 2;
    float4 a = src[0], b = src[1];
    uint4n u;
    u.x = bf16pair(a.x, a.y); u.y = bf16pair(a.z, a.w);
    u.z = bf16pair(b.x, b.y); u.w = bf16pair(b.z, b.w);
    reinterpret_cast<uint4n*>(f16)[i] = u;
}

// ---------- Phase A1: histogram (k, in_row chunk) ----------
__global__ __launch_bounds__(256) void histc_kernel(
    const int* __restrict__ in_map, int* __restrict__ cntc)
{
    __shared__ int h[NBINC];                 // 21 KB
    const int t = threadIdx.x;
    const int base = blockIdx.x * BPB;
    for (int c = t; c < NBINC; c += 256) h[c] = 0;
    __syncthreads();
    for (int i = t; i < BPB; i += 256) {
        int p = base + i;
        if (p < NPAIR) {
            int key = (p / MPAIR) * NCHUNK + (in_map[p] >> 10);
            atomicAdd(&h[key], 1);
        }
    }
    __syncthreads();
    for (int c = t; c < NBINC; c += 256) if (h[c]) atomicAdd(&cntc[c], h[c]);
}

// ---------- Phase A2: exclusive scan over 5292 bins (single block) ----------
__global__ __launch_bounds__(256) void scanc_kernel(
    const int* __restrict__ cntc, int* __restrict__ basc, int* __restrict__ curc)
{
    __shared__ int lsum[256];
    const int t = threadIdx.x;
    int v[21]; int s = 0;
#pragma unroll
    for (int j = 0; j < 21; ++j) {
        int i = t * 21 + j;
        v[j] = (i < NBINC) ? cntc[i] : 0;
        s += v[j];
    }
    lsum[t] = s;
    __syncthreads();
    for (int off = 1; off < 256; off <<= 1) {
        int w = (t >= off) ? lsum[t - off] : 0;
        __syncthreads();
        lsum[t] += w;
        __syncthreads();
    }
    int run = lsum[t] - s;
#pragma unroll
    for (int j = 0; j < 21; ++j) {
        int i = t * 21 + j;
        if (i < NBINC) { basc[i] = run; curc[i] = run; run += v[j]; }
    }
    if (t == 255) basc[NBINC] = run;
}

// ---------- Phase A3: chunk-local scatter into (k,chunk) bins ----------
__global__ __launch_bounds__(256) void scatc_kernel(
    const int* __restrict__ in_map, int* __restrict__ curc,
    unsigned int* __restrict__ binned_in)
{
    __shared__ int h[NBINC];                 // count, then absolute cursor
    const int t = threadIdx.x;
    const int base = blockIdx.x * BPB;
    for (int c = t; c < NBINC; c += 256) h[c] = 0;
    __syncthreads();
    for (int i = t; i < BPB; i += 256) {
        int p = base + i;
        if (p < NPAIR)
            atomicAdd(&h[(p / MPAIR) * NCHUNK + (in_map[p] >> 10)], 1);
    }
    __syncthreads();
    for (int c = t; c < NBINC; c += 256) {
        int v = h[c];
        h[c] = v ? atomicAdd(&curc[c], v) : 0;   // reserve chunk -> abs base
    }
    __syncthreads();
    for (int i = t; i < BPB; i += 256) {
        int p = base + i;
        if (p >= NPAIR) continue;
        int ir = in_map[p];
        int key = (p / MPAIR) * NCHUNK + (ir >> 10);
        int slot = atomicAdd(&h[key], 1);
        binned_in[slot] = ((unsigned int)(ir & 1023) << 22) | (unsigned int)p;
    }
}

// ---------- Phase 1: multisplit pair ids by output-row bin ----------
__global__ __launch_bounds__(256) void bin_kernel(
    const int* __restrict__ out_map,
    int* __restrict__ gbin, int* __restrict__ binned,
    int* __restrict__ spill_cnt, int2* __restrict__ spill)
{
    __shared__ int lhist[NBIN];
    const int t = threadIdx.x;
    const int base = blockIdx.x * BPB;

    for (int c = t; c < NBIN; c += 256) lhist[c] = 0;
    __syncthreads();

    for (int i = t; i < BPB; i += 256) {
        int p = base + i;
        if (p < NPAIR) atomicAdd(&lhist[out_map[p] >> 8], 1);
    }
    __syncthreads();

    for (int c = t; c < NBIN; c += 256) {
        int cnt = lhist[c];
        lhist[c] = (cnt > 0) ? atomicAdd(&gbin[c], cnt) : 0;
    }
    __syncthreads();

    for (int i = t; i < BPB; i += 256) {
        int p = base + i;
        if (p >= NPAIR) continue;
        int row = out_map[p];
        int bin = row >> 8;
        int val = ((row & 255) << 22) | p;       // max bit 29: sign-safe
        int pos = atomicAdd(&lhist[bin], 1);
        if (pos < CAPB) {
            binned[(size_t)bin * CAPB + pos] = val;
        } else {
            int o = atomicAdd(spill_cnt, 1);
            if (o < SPILL_CAP) spill[o] = make_int2(row, p);
        }
    }
}

// ---------- Phase 2: mv3 — UNIFORM loop, predicated lanes, 8ch-block unpack ----------
__global__ __launch_bounds__(256) void mv3_kernel(
    const unsigned short* __restrict__ f16, const float* __restrict__ weight,
    const int* __restrict__ basc, const unsigned int* __restrict__ binned_in,
    unsigned short* __restrict__ per_off)
{
    // XCD-swizzled bin mapping: 27 k-bins of one chunk land on one XCD.
    int g = blockIdx.x;
    int k, chunk;
    if (g < 24 * 216) {
        int grp = g / 216, rem = g % 216;
        k = rem >> 3;                       // 0..26
        chunk = grp * 8 + (rem & 7);
    } else {
        int tl = g - 24 * 216;              // 0..107
        k = tl >> 2;
        chunk = 192 + (tl & 3);
    }
    k = __builtin_amdgcn_readfirstlane(k);
    chunk = __builtin_amdgcn_readfirstlane(chunk);

    const int key = k * NCHUNK + chunk;
    const int s0 = basc[key], s1 = basc[key + 1];
    const int nwork = s1 - s0;               // wave-uniform
    const int t = threadIdx.x;

    const float* wk = weight + (size_t)k * (CIN * COUT);

    // UNIFORM trip count: divergence confined to predicated index/store.
    for (int ib = 0; ib < nwork; ib += 256) {
        const bool act = (ib + t) < nwork;
        const int i = s0 + (act ? ib + t : 0);
        unsigned int e = binned_in[i];
        int rl = (int)(e >> 22);
        int p  = (int)(e & 0x3FFFFFu);
        int row = (chunk << 10) + rl;        // inside 64 KB L2-hot window

        const uint4n* frow = reinterpret_cast<const uint4n*>(f16 + (size_t)row * CIN);
        uint4n q0 = frow[0], q1 = frow[1], q2 = frow[2], q3 = frow[3];  // MLP4

        float acc[COUT];
#pragma unroll
        for (int j = 0; j < COUT; ++j) acc[j] = 0.f;

        // 8 channels at a time: only 8 unpacked floats live -> low VGPR pressure
#define DO8(Q, CI0)                                                         \
        {                                                                   \
            float f0 = bf2f_lo(Q.x), f1 = bf2f_hi(Q.x);                     \
            float f2 = bf2f_lo(Q.y), f3 = bf2f_hi(Q.y);                     \
            float f4v = bf2f_lo(Q.z), f5 = bf2f_hi(Q.z);                    \
            float f6 = bf2f_lo(Q.w), f7 = bf2f_hi(Q.w);                     \
            _Pragma("unroll")                                               \
            for (int co = 0; co < COUT; ++co) {                             \
                float a = acc[co];                                          \
                a = fmaf(f0, wk[(CI0 + 0) * COUT + co], a);                 \
                a = fmaf(f1, wk[(CI0 + 1) * COUT + co], a);                 \
                a = fmaf(f2, wk[(CI0 + 2) * COUT + co], a);                 \
                a = fmaf(f3, wk[(CI0 + 3) * COUT + co], a);                 \
                a = fmaf(f4v, wk[(CI0 + 4) * COUT + co], a);                \
                a = fmaf(f5, wk[(CI0 + 5) * COUT + co], a);                 \
                a = fmaf(f6, wk[(CI0 + 6) * COUT + co], a);                 \
                a = fmaf(f7, wk[(CI0 + 7) * COUT + co], a);                 \
                acc[co] = a;                                                \
            }                                                               \
        }
        DO8(q0, 0)
        DO8(q1, 8)
        DO8(q2, 16)
        DO8(q3, 24)
#undef DO8

        if (act) {
            uint4n u;
            uint4n* dst = reinterpret_cast<uint4n*>(per_off + (size_t)p * COUT);
#pragma unroll
            for (int j = 0; j < 4; ++j) {
                u.x = bf16pair(acc[8 * j + 0], acc[8 * j + 1]);
                u.y = bf16pair(acc[8 * j + 2], acc[8 * j + 3]);
                u.z = bf16pair(acc[8 * j + 4], acc[8 * j + 5]);
                u.w = bf16pair(acc[8 * j + 6], acc[8 * j + 7]);
                dst[j] = u;                  // random 64B store, fire-and-forget
            }
        }
    }
}

// ---------- Phase 3: per-bin counting-sort + ILP4 gather ----------
__global__ __launch_bounds__(256) void gather3_kernel(
    const unsigned short* __restrict__ per_off,
    const int* __restrict__ gbin, const int* __restrict__ binned,
    float* __restrict__ out)
{
    __shared__ int sorted[CAPB];             // 12 KB
    __shared__ int cnt[ROWS_PER_BIN];
    __shared__ int scn[ROWS_PER_BIN];
    __shared__ int cur[ROWS_PER_BIN];

    const int bin = blockIdx.x;
    const int t = threadIdx.x;
    const int n = min(gbin[bin], CAPB);
    const int* mybin = binned + (size_t)bin * CAPB;

    cnt[t] = 0;
    __syncthreads();

    for (int i = t; i < n; i += 256)
        atomicAdd(&cnt[(mybin[i] >> 22) & 255], 1);
    __syncthreads();

    scn[t] = cnt[t];
    __syncthreads();
#pragma unroll
    for (int off = 1; off < 256; off <<= 1) {
        int v = (t >= off) ? scn[t - off] : 0;
        __syncthreads();
        scn[t] += v;
        __syncthreads();
    }
    cur[t] = scn[t] - cnt[t];
    __syncthreads();

    for (int i = t; i < n; i += 256) {
        int v = mybin[i];
        int pos = atomicAdd(&cur[(v >> 22) & 255], 1);
        sorted[pos] = v & 0x3FFFFF;
    }
    __syncthreads();

    const int g = t >> 5, lane = t & 31;
    for (int r = g; r < ROWS_PER_BIN; r += 8) {
        int grow = (bin << 8) + r;
        if (grow >= NOUT) break;
        int s1 = scn[r], s0 = s1 - cnt[r];
        float a0 = 0.f, a1 = 0.f, a2 = 0.f, a3 = 0.f;
        int i = s0;
        for (; i + 4 <= s1; i += 4) {
            int p0 = sorted[i], p1 = sorted[i + 1], p2 = sorted[i + 2], p3 = sorted[i + 3];
            a0 += bf2f(per_off[(size_t)p0 * COUT + lane]);
            a1 += bf2f(per_off[(size_t)p1 * COUT + lane]);
            a2 += bf2f(per_off[(size_t)p2 * COUT + lane]);
            a3 += bf2f(per_off[(size_t)p3 * COUT + lane]);
        }
        for (; i < s1; ++i)
            a0 += bf2f(per_off[(size_t)sorted[i] * COUT + lane]);
        out[(size_t)grow * COUT + lane] = (a0 + a1) + (a2 + a3);
    }
}

// ---------- Phase 4: rare out-bin overflow, recompute + atomics ----------
__global__ __launch_bounds__(256) void spill_kernel(
    const float* __restrict__ feats, const float* __restrict__ weight,
    const int* __restrict__ in_map,
    const int* __restrict__ spill_cnt, const int2* __restrict__ spill,
    float* __restrict__ out)
{
    int n = min(*spill_cnt, SPILL_CAP);
    for (int i = blockIdx.x * blockDim.x + threadIdx.x; i < n * 32;
         i += gridDim.x * blockDim.x) {
        int idx = i >> 5, co = i & 31;
        int2 s = spill[idx];
        int row = s.x;
        int p   = s.y;
        int k   = p / MPAIR;
        int irow = in_map[p];
        const float* f  = feats + (size_t)irow * CIN;
        const float* wk = weight + (size_t)k * (CIN * COUT);
        float acc = 0.f;
#pragma unroll
        for (int ci = 0; ci < CIN; ++ci)
            acc = fmaf(f[ci], wk[ci * COUT + co], acc);
        atomicAdd(&out[(size_t)row * COUT + co], acc);
    }
}

// ---------- last-resort fallback (tiny ws): R1 atomic scatter ----------
__global__ __launch_bounds__(256) void spconvt_fallback(
    const float* __restrict__ feats, const float* __restrict__ weight,
    const int* __restrict__ in_map, const int* __restrict__ out_map,
    float* __restrict__ out)
{
    const int k = blockIdx.y;
    const int m = blockIdx.x * blockDim.x + threadIdx.x;
    const bool active = (m < MPAIR);
    const int mm = active ? m : (MPAIR - 1);
    const int pair = k * MPAIR + mm;
    const int in_row = in_map[pair];
    const int out_row = out_map[pair];
    const float4* frow = reinterpret_cast<const float4*>(feats + (size_t)in_row * CIN);
    float4 f4[8];
#pragma unroll
    for (int i = 0; i < 8; ++i) f4[i] = frow[i];
    const float* f = reinterpret_cast<const float*>(f4);
    float acc[COUT];
#pragma unroll
    for (int i = 0; i < COUT; ++i) acc[i] = 0.f;
    const float* wk = weight + (size_t)k * (CIN * COUT);
#pragma unroll
    for (int ci = 0; ci < CIN; ++ci) {
        const float fv = f[ci];
#pragma unroll
        for (int co = 0; co < COUT; ++co)
            acc[co] = fmaf(fv, wk[ci * COUT + co], acc[co]);
    }
    if (active) {
        float* orow = out + (size_t)out_row * COUT;
#pragma unroll
        for (int co = 0; co < COUT; ++co) atomicAdd(orow + co, acc[co]);
    }
}

extern "C" void kernel_launch(void* const* d_in, const int* in_sizes, int n_in,
                              void* d_out, int out_size, void* d_ws, size_t ws_size,
                              hipStream_t stream) {
    const float* feats  = (const float*)d_in[0];
    const float* weight = (const float*)d_in[1];
    const int* in_map   = (const int*)d_in[2];
    const int* out_map  = (const int*)d_in[3];
    float* out          = (float*)d_out;
    char* ws            = (char*)d_ws;

    if (ws_size >= WS_NEED) {
        int* gbin               = (int*)(ws);
        int* cntc               = (int*)(ws + O_CNTC);
        int* spill_cnt          = (int*)(ws + O_SPCNT);
        int2* spill             = (int2*)(ws + O_SPILL);
        int* basc               = (int*)(ws + O_BASC);
        int* curc               = (int*)(ws + O_CURC);
        int* binned             = (int*)(ws + O_BINNED);
        unsigned int* binned_in = (unsigned int*)(ws + O_BINI);
        unsigned short* per_off = (unsigned short*)(ws + O_PEROFF);
        unsigned short* f16     = (unsigned short*)(ws + O_F16);

        (void)hipMemsetAsync(ws, 0, O_SPILL, stream);   // gbin + cntc + spill_cnt

        cvt_kernel<<<dim3((NIN * CIN / 8 + 255) / 256), dim3(256), 0, stream>>>(
            feats, f16);

        histc_kernel<<<dim3((NPAIR + BPB - 1) / BPB), dim3(256), 0, stream>>>(
            in_map, cntc);
        scanc_kernel<<<dim3(1), dim3(256), 0, stream>>>(cntc, basc, curc);
        scatc_kernel<<<dim3((NPAIR + BPB - 1) / BPB), dim3(256), 0, stream>>>(
            in_map, curc, binned_in);

        bin_kernel<<<dim3((NPAIR + BPB - 1) / BPB), dim3(256), 0, stream>>>(
            out_map, gbin, binned, spill_cnt, spill);

        mv3_kernel<<<dim3(NBINC), dim3(256), 0, stream>>>(
            f16, weight, basc, binned_in, per_off);

        gather3_kernel<<<dim3(NBIN), dim3(256), 0, stream>>>(
            per_off, gbin, binned, out);

        spill_kernel<<<dim3(64), dim3(256), 0, stream>>>(
            feats, weight, in_map, spill_cnt, spill, out);
    } else {
        (void)hipMemsetAsync(d_out, 0, (size_t)out_size * sizeof(float), stream);
        spconvt_fallback<<<dim3((MPAIR + 255) / 256, KOFF), dim3(256), 0, stream>>>(
            feats, weight, in_map, out_map, out);
    }
}